// Round 4
// baseline (194.450 us; speedup 1.0000x reference)
//
#include <hip/hip_runtime.h>

#define BTOT 4194304
#define MPW 4   // 64-row macro-groups per wave

typedef __attribute__((ext_vector_type(4))) float f32x4;
typedef __attribute__((ext_vector_type(8))) short bf16x8;

#define KLOG 2.88539008177792681472f  // 2*log2(e)
#define YCLAMP 30.0f                  // tanh saturated below 1e-9 here; keeps 4-way products finite

__device__ __forceinline__ short f2bf(float f) {   // RNE, setup only
  union { float f; unsigned u; } v; v.f = f;
  unsigned u = v.u;
  unsigned r = (u + 0x7FFFu + ((u >> 16) & 1u)) >> 16;
  return (short)r;
}
__device__ __forceinline__ float bf2f(short s) {
  union { unsigned u; float f; } v; v.u = ((unsigned)(unsigned short)s) << 16;
  return v.f;
}

// 4 tanh from PRE-SCALED pre-clamped inputs y_i = min(2log2e*x_i, 30):
// tanh_i = 1 - 2/(1+2^y_i), with ONE v_rcp for all four via prefix/suffix products.
__device__ __forceinline__ void tanh_b4(const float* y, float* o) {
  float u0 = 1.0f + __builtin_amdgcn_exp2f(y[0]);
  float u1 = 1.0f + __builtin_amdgcn_exp2f(y[1]);
  float u2 = 1.0f + __builtin_amdgcn_exp2f(y[2]);
  float u3 = 1.0f + __builtin_amdgcn_exp2f(y[3]);
  float p01  = u0 * u1;
  float p012 = p01 * u2;
  float P    = p012 * u3;
  float r  = __builtin_amdgcn_rcpf(P);
  float i3 = r * p012;          // 1/u3
  float r3 = r * u3;            // 1/(u0 u1 u2)
  float i2 = r3 * p01;          // 1/u2
  float r2 = r3 * u2;           // 1/(u0 u1)
  float i1 = r2 * u0;           // 1/u1
  float i0 = r2 * u1;           // 1/u0
  o[0] = __builtin_fmaf(-2.0f, i0, 1.0f);
  o[1] = __builtin_fmaf(-2.0f, i1, 1.0f);
  o[2] = __builtin_fmaf(-2.0f, i2, 1.0f);
  o[3] = __builtin_fmaf(-2.0f, i3, 1.0f);
}

// Pack 8 floats into hi/lo bf16x8 fragments via truncate-split + v_perm word packing.
__device__ __forceinline__ void pack_hilo(const float* h, bf16x8& bh, bf16x8& bl) {
  union U { unsigned w[4]; bf16x8 v; } H, L;
  #pragma unroll
  for (int jw = 0; jw < 4; ++jw) {
    float h0 = h[2 * jw], h1 = h[2 * jw + 1];
    unsigned u0 = __builtin_bit_cast(unsigned, h0);
    unsigned u1 = __builtin_bit_cast(unsigned, h1);
    float hi0 = __builtin_bit_cast(float, u0 & 0xFFFF0000u);
    float hi1 = __builtin_bit_cast(float, u1 & 0xFFFF0000u);
    float lo0 = h0 - hi0;                   // exact residual
    float lo1 = h1 - hi1;
    unsigned v0 = __builtin_bit_cast(unsigned, lo0);
    unsigned v1 = __builtin_bit_cast(unsigned, lo1);
    H.w[jw] = __builtin_amdgcn_perm(u1, u0, 0x07060302u);  // [hi16(h1)|hi16(h0)]
    L.w[jw] = __builtin_amdgcn_perm(v1, v0, 0x07060302u);
  }
  bh = H.v; bl = L.v;
}

__global__ __launch_bounds__(256, 4)
void damping_kernel(const float* __restrict__ x,
                    const float* __restrict__ w_d1, const float* __restrict__ w_d2,
                    const float* __restrict__ w_d3, const float* __restrict__ w_o1,
                    const float* __restrict__ w_o2, const float* __restrict__ w_o3,
                    const float* __restrict__ b_d1, const float* __restrict__ b_d2,
                    const float* __restrict__ b_d3, const float* __restrict__ b_o1,
                    const float* __restrict__ b_o2, const float* __restrict__ b_o3,
                    float* __restrict__ out)
{
  const int tid  = blockIdx.x * blockDim.x + threadIdx.x;
  const int wave = tid >> 6;
  const int l    = threadIdx.x & 63;
  const int g    = l >> 4;      // k-group 0..3
  const int c16  = l & 15;      // row-in-tile (B/A lane dim)
  const int kbase = g * 8;

  // ---- per-lane constants ----
  // Layer-1 weights PRE-SCALED by 2*log2(e).
  float W0[8], W1[8], B1[8];
  #pragma unroll
  for (int j = 0; j < 8; ++j) {
    int f = kbase + j;
    if (f < 16) { W0[j] = KLOG * w_d1[f];      W1[j] = KLOG * w_d1[16 + f];      B1[j] = KLOG * b_d1[f]; }
    else        { W0[j] = KLOG * w_o1[f - 16]; W1[j] = KLOG * w_o1[16 + f - 16]; B1[j] = KLOG * b_o1[f - 16]; }
  }
  // Layer-2 A-operand = (KLOG * w2)^T zero-padded per net, RNE hi/lo split.
  bf16x8 Adh, Adl, Aoh, Aol;
  #pragma unroll
  for (int j = 0; j < 8; ++j) {
    int k = kbase + j;
    float ad = (k < 16)  ? KLOG * w_d2[k * 16 + c16]        : 0.0f;
    float ao = (k >= 16) ? KLOG * w_o2[(k - 16) * 16 + c16] : 0.0f;
    short adh = f2bf(ad); Adh[j] = adh; Adl[j] = f2bf(ad - bf2f(adh));
    short aoh = f2bf(ao); Aoh[j] = aoh; Aol[j] = f2bf(ao - bf2f(aoh));
  }
  // Layer-2 MFMA C-init = pre-scaled bias; C[r=(g*4+i)][c16]
  f32x4 Cd0, Co0;
  #pragma unroll
  for (int i = 0; i < 4; ++i) {
    int f = g * 4 + i;
    Cd0[i] = KLOG * b_d2[f]; Co0[i] = KLOG * b_o2[f];
  }

  // Layer-3 A-operand variants. For tile t, A_t[row][k] nonzero only for
  // rows 4t..4t+2:  row 4t+0 -> w_d3[:,0], 4t+1 -> w_d3[:,1], 4t+2 -> w_o3.
  // k = 8g+j: j<4 -> d-net feat 4g+j, j>=4 -> o-net feat 4g+j-4.
  // Per lane (A[row=c16][k=8g+j]) only the variant t == c16>>2 is nonzero.
  const int rr = c16 & 3, tt = c16 >> 2;
  bf16x8 A3h[4], A3l[4];
  #pragma unroll
  for (int t = 0; t < 4; ++t) {
    #pragma unroll
    for (int j = 0; j < 8; ++j) {
      float val = 0.0f;
      if (t == tt) {
        if (rr == 0 && j < 4)  val = w_d3[(4 * g + j) * 2 + 0];
        if (rr == 1 && j < 4)  val = w_d3[(4 * g + j) * 2 + 1];
        if (rr == 2 && j >= 4) val = w_o3[4 * g + j - 4];
      }
      short vh = f2bf(val);
      A3h[t][j] = vh;
      A3l[t][j] = f2bf(val - bf2f(vh));
    }
  }
  // acc3 C-init (per-lane uniform): rows 4g+{0,1,2} biases
  const float b30 = b_d3[0], b31 = b_d3[1], b3o = b_o3[0];

  for (int m = 0; m < MPW; ++m) {
    const int mbase = (wave * MPW + m) * 64;

    // preload the 4 x-tiles
    float2 xv4[4];
    #pragma unroll
    for (int t = 0; t < 4; ++t)
      xv4[t] = ((const float2*)x)[mbase + t * 16 + c16];

    f32x4 acc3;
    acc3[0] = b30; acc3[1] = b31; acc3[2] = b3o; acc3[3] = 0.0f;

    #pragma unroll
    for (int t = 0; t < 4; ++t) {
      const float2 xv = xv4[t];

      // layer 1 preact (pre-scaled) + clamp
      float y[8];
      #pragma unroll
      for (int j = 0; j < 8; ++j)
        y[j] = fminf(__builtin_fmaf(xv.y, W1[j], __builtin_fmaf(xv.x, W0[j], B1[j])), YCLAMP);
      // tanh via batched rcp (2 batches of 4)
      float h[8];
      tanh_b4(y, h);
      tanh_b4(y + 4, h + 4);

      bf16x8 bh, bl;
      pack_hilo(h, bh, bl);

      // layer 2: d2^T via 3-MFMA hi/lo split per net
      f32x4 accd = Cd0, acco = Co0;
      accd = __builtin_amdgcn_mfma_f32_16x16x32_bf16(Adh, bh, accd, 0, 0, 0);
      acco = __builtin_amdgcn_mfma_f32_16x16x32_bf16(Aoh, bh, acco, 0, 0, 0);
      accd = __builtin_amdgcn_mfma_f32_16x16x32_bf16(Adh, bl, accd, 0, 0, 0);
      acco = __builtin_amdgcn_mfma_f32_16x16x32_bf16(Aoh, bl, acco, 0, 0, 0);
      accd = __builtin_amdgcn_mfma_f32_16x16x32_bf16(Adl, bh, accd, 0, 0, 0);
      acco = __builtin_amdgcn_mfma_f32_16x16x32_bf16(Aol, bh, acco, 0, 0, 0);

      // layer-2 tanh (inputs pre-scaled via A/C) + clamp
      float y2[8];
      #pragma unroll
      for (int i = 0; i < 4; ++i) {
        y2[i]     = fminf(accd[i], YCLAMP);
        y2[4 + i] = fminf(acco[i], YCLAMP);
      }
      float h2[8];
      tanh_b4(y2, h2);
      tanh_b4(y2 + 4, h2 + 4);

      bf16x8 b3h, b3l;
      pack_hilo(h2, b3h, b3l);

      // layer 3: accumulate rows 4t..4t+2 of [a,b,c] into acc3 (hi/lo split)
      acc3 = __builtin_amdgcn_mfma_f32_16x16x32_bf16(A3h[t], b3h, acc3, 0, 0, 0);
      acc3 = __builtin_amdgcn_mfma_f32_16x16x32_bf16(A3h[t], b3l, acc3, 0, 0, 0);
      acc3 = __builtin_amdgcn_mfma_f32_16x16x32_bf16(A3l[t], b3h, acc3, 0, 0, 0);
    }

    // epilogue ONCE per 64 rows: lane l holds (a_pre,b_pre,c) for row mbase+l
    const float2 xs = ((const float2*)x)[mbase + l];
    float a = (fmaxf(acc3[0], 0.0f) + 0.001f) * xs.x;
    float b = (fmaxf(acc3[1], 0.0f) + 0.001f) * xs.y;
    float c = acc3[2];
    float D0 = a * __builtin_fmaf(a, xs.x, c * xs.y);
    float s  = __builtin_fmaf(c, c, b * b);
    float D1 = __builtin_fmaf(a * c, xs.x, s * xs.y);
    ((float2*)out)[mbase + l] = make_float2(D0, D1);  // coalesced 512B/wave
  }
}

extern "C" void kernel_launch(void* const* d_in, const int* in_sizes, int n_in,
                              void* d_out, int out_size, void* d_ws, size_t ws_size,
                              hipStream_t stream) {
  const float* x    = (const float*)d_in[0];
  const float* w_d1 = (const float*)d_in[1];
  const float* w_d2 = (const float*)d_in[2];
  const float* w_d3 = (const float*)d_in[3];
  const float* w_o1 = (const float*)d_in[4];
  const float* w_o2 = (const float*)d_in[5];
  const float* w_o3 = (const float*)d_in[6];
  const float* b_d1 = (const float*)d_in[7];
  const float* b_d2 = (const float*)d_in[8];
  const float* b_d3 = (const float*)d_in[9];
  const float* b_o1 = (const float*)d_in[10];
  const float* b_o2 = (const float*)d_in[11];
  const float* b_o3 = (const float*)d_in[12];
  float* out = (float*)d_out;

  const int waves  = BTOT / (64 * MPW);  // 16384
  const int blocks = waves / 4;          // 4096 blocks of 256 threads
  damping_kernel<<<blocks, 256, 0, stream>>>(x, w_d1, w_d2, w_d3, w_o1, w_o2, w_o3,
                                             b_d1, b_d2, b_d3, b_o1, b_o2, b_o3, out);
}

// Round 5
// 165.211 us; speedup vs baseline: 1.1770x; 1.1770x over previous
//
#include <hip/hip_runtime.h>

#define BTOT 4194304
#define MPW 4   // 64-row macro-groups per wave

typedef __attribute__((ext_vector_type(4))) float f32x4;
typedef __attribute__((ext_vector_type(8))) short bf16x8;

#define KLOG 2.88539008177792681472f  // 2*log2(e)

__device__ __forceinline__ short f2bf(float f) {   // RNE, setup only
  union { float f; unsigned u; } v; v.f = f;
  unsigned u = v.u;
  unsigned r = (u + 0x7FFFu + ((u >> 16) & 1u)) >> 16;
  return (short)r;
}
__device__ __forceinline__ float bf2f(short s) {
  union { unsigned u; float f; } v; v.u = ((unsigned)(unsigned short)s) << 16;
  return v.f;
}

// tanh from PRE-SCALED input y = 2*log2(e)*x: tanh = 1 - 2/(1+2^y).
// No clamp needed: exp2->inf/0 saturates exactly through rcp (R3-verified).
__device__ __forceinline__ float tanh_pre(float y) {
  float t = __builtin_amdgcn_exp2f(y);
  float r = __builtin_amdgcn_rcpf(1.0f + t);
  return __builtin_fmaf(-2.0f, r, 1.0f);
}

// One-instruction RNE pack of 2 floats -> packed bf16 pair (low = first arg).
__device__ __forceinline__ unsigned cvt_pk(float lo, float hi) {
  unsigned r;
  asm("v_cvt_pk_bf16_f32 %0, %1, %2" : "=v"(r) : "v"(lo), "v"(hi));
  return r;
}
// 8 floats -> bf16x8 fragment in 4 ops.
__device__ __forceinline__ bf16x8 pack8(const float* h) {
  union { unsigned w[4]; bf16x8 v; } U;
  #pragma unroll
  for (int jw = 0; jw < 4; ++jw) U.w[jw] = cvt_pk(h[2 * jw], h[2 * jw + 1]);
  return U.v;
}

__global__ __launch_bounds__(256, 4)
void damping_kernel(const float* __restrict__ x,
                    const float* __restrict__ w_d1, const float* __restrict__ w_d2,
                    const float* __restrict__ w_d3, const float* __restrict__ w_o1,
                    const float* __restrict__ w_o2, const float* __restrict__ w_o3,
                    const float* __restrict__ b_d1, const float* __restrict__ b_d2,
                    const float* __restrict__ b_d3, const float* __restrict__ b_o1,
                    const float* __restrict__ b_o2, const float* __restrict__ b_o3,
                    float* __restrict__ out)
{
  const int tid  = blockIdx.x * blockDim.x + threadIdx.x;
  const int wave = tid >> 6;
  const int l    = threadIdx.x & 63;
  const int g    = l >> 4;      // k-group 0..3
  const int c16  = l & 15;      // row-in-tile / A-row / C-col
  const int kbase = g * 8;

  // ---- per-lane constants (setup once, amortized over 16 t-iters) ----
  // Layer-1 weights PRE-SCALED by 2*log2(e); f<16 -> d-net, f>=16 -> o-net.
  float W0[8], W1[8], B1[8];
  #pragma unroll
  for (int j = 0; j < 8; ++j) {
    int f = kbase + j;
    if (f < 16) { W0[j] = KLOG * w_d1[f];      W1[j] = KLOG * w_d1[16 + f];      B1[j] = KLOG * b_d1[f]; }
    else        { W0[j] = KLOG * w_o1[f - 16]; W1[j] = KLOG * w_o1[16 + f - 16]; B1[j] = KLOG * b_o1[f - 16]; }
  }
  // Layer-2 A = (KLOG*w2)^T zero-padded per net, hi/lo split (weights only).
  bf16x8 Adh, Adl, Aoh, Aol;
  #pragma unroll
  for (int j = 0; j < 8; ++j) {
    int k = kbase + j;
    float ad = (k < 16)  ? KLOG * w_d2[k * 16 + c16]        : 0.0f;
    float ao = (k >= 16) ? KLOG * w_o2[(k - 16) * 16 + c16] : 0.0f;
    short adh = f2bf(ad); Adh[j] = adh; Adl[j] = f2bf(ad - bf2f(adh));
    short aoh = f2bf(ao); Aoh[j] = aoh; Aol[j] = f2bf(ao - bf2f(aoh));
  }
  // Layer-2 C-init = pre-scaled bias; C[r=4g+i][c16]
  f32x4 Cd0, Co0;
  #pragma unroll
  for (int i = 0; i < 4; ++i) {
    int f = g * 4 + i;
    Cd0[i] = KLOG * b_d2[f]; Co0[i] = KLOG * b_o2[f];
  }

  // Layer-3 A-operand, 4 tile-variants (bf16 only; w3 rep err negligible).
  // A_t[row][k] nonzero rows 4t..4t+2: row 4t->w_d3[:,0], 4t+1->w_d3[:,1], 4t+2->w_o3.
  // k = 8g+j: j<4 -> d-feat 4g+j, j>=4 -> o-feat 4g+j-4. Lane supplies A[c16][8g+j].
  const int rr = c16 & 3, tt = c16 >> 2;
  bf16x8 A3h[4];
  #pragma unroll
  for (int t = 0; t < 4; ++t) {
    #pragma unroll
    for (int j = 0; j < 8; ++j) {
      float val = 0.0f;
      if (t == tt) {
        if (rr == 0 && j < 4)  val = w_d3[(4 * g + j) * 2 + 0];
        if (rr == 1 && j < 4)  val = w_d3[(4 * g + j) * 2 + 1];
        if (rr == 2 && j >= 4) val = w_o3[4 * g + j - 4];
      }
      A3h[t][j] = f2bf(val);
    }
  }
  const float b30 = b_d3[0], b31 = b_d3[1], b3o = b_o3[0];

  const float2* x2 = (const float2*)x;

  for (int m = 0; m < MPW; ++m) {
    const int mbase = (wave * MPW + m) * 64;

    // preload the 4 x-tiles
    float2 xv4[4];
    #pragma unroll
    for (int t = 0; t < 4; ++t)
      xv4[t] = x2[mbase + t * 16 + c16];

    f32x4 acc3;
    acc3[0] = b30; acc3[1] = b31; acc3[2] = b3o; acc3[3] = 0.0f;

    #pragma unroll
    for (int t = 0; t < 4; ++t) {
      const float2 xv = xv4[t];

      // layer 1 (pre-scaled) + tanh: 8 feats/lane
      float h[8];
      #pragma unroll
      for (int j = 0; j < 8; ++j)
        h[j] = tanh_pre(__builtin_fmaf(xv.y, W1[j], __builtin_fmaf(xv.x, W0[j], B1[j])));

      bf16x8 b1f = pack8(h);   // 4 cvt_pk

      // layer 2: weights hi/lo x activation single (4 MFMA)
      f32x4 accd = Cd0, acco = Co0;
      accd = __builtin_amdgcn_mfma_f32_16x16x32_bf16(Adh, b1f, accd, 0, 0, 0);
      accd = __builtin_amdgcn_mfma_f32_16x16x32_bf16(Adl, b1f, accd, 0, 0, 0);
      acco = __builtin_amdgcn_mfma_f32_16x16x32_bf16(Aoh, b1f, acco, 0, 0, 0);
      acco = __builtin_amdgcn_mfma_f32_16x16x32_bf16(Aol, b1f, acco, 0, 0, 0);

      // layer-2 tanh (inputs pre-scaled via A/C)
      float h2[8];
      #pragma unroll
      for (int i = 0; i < 4; ++i) {
        h2[i]     = tanh_pre(accd[i]);
        h2[4 + i] = tanh_pre(acco[i]);
      }
      bf16x8 b3f = pack8(h2);  // 4 cvt_pk

      // layer 3: accumulate rows 4t..4t+2 of [a_pre,b_pre,c] (1 MFMA)
      acc3 = __builtin_amdgcn_mfma_f32_16x16x32_bf16(A3h[t], b3f, acc3, 0, 0, 0);
    }

    // epilogue once per 64 rows: lane l holds (a_pre,b_pre,c) for row mbase+l
    const float2 xs = x2[mbase + l];
    float a = (fmaxf(acc3[0], 0.0f) + 0.001f) * xs.x;
    float b = (fmaxf(acc3[1], 0.0f) + 0.001f) * xs.y;
    float c = acc3[2];
    float D0 = a * __builtin_fmaf(a, xs.x, c * xs.y);
    float s  = __builtin_fmaf(c, c, b * b);
    float D1 = __builtin_fmaf(a * c, xs.x, s * xs.y);
    ((float2*)out)[mbase + l] = make_float2(D0, D1);  // coalesced 512B/wave
  }
}

extern "C" void kernel_launch(void* const* d_in, const int* in_sizes, int n_in,
                              void* d_out, int out_size, void* d_ws, size_t ws_size,
                              hipStream_t stream) {
  const float* x    = (const float*)d_in[0];
  const float* w_d1 = (const float*)d_in[1];
  const float* w_d2 = (const float*)d_in[2];
  const float* w_d3 = (const float*)d_in[3];
  const float* w_o1 = (const float*)d_in[4];
  const float* w_o2 = (const float*)d_in[5];
  const float* w_o3 = (const float*)d_in[6];
  const float* b_d1 = (const float*)d_in[7];
  const float* b_d2 = (const float*)d_in[8];
  const float* b_d3 = (const float*)d_in[9];
  const float* b_o1 = (const float*)d_in[10];
  const float* b_o2 = (const float*)d_in[11];
  const float* b_o3 = (const float*)d_in[12];
  float* out = (float*)d_out;

  const int waves  = BTOT / (64 * MPW);  // 16384
  const int blocks = waves / 4;          // 4096 blocks of 256 threads
  damping_kernel<<<blocks, 256, 0, stream>>>(x, w_d1, w_d2, w_d3, w_o1, w_o2, w_o3,
                                             b_d1, b_d2, b_d3, b_o1, b_o2, b_o3, out);
}